// Round 1
// baseline (132.135 us; speedup 1.0000x reference)
//
#include <hip/hip_runtime.h>
#include <cstddef>

#define LDW 68  // padded LDS leading dim (floats), multiple of 4 for float4

// ======================================================================
// GNN: per-molecule message passing + pooling + fc.  grid=128, block=512
// ======================================================================
#define GNN_STEP(XC) { \
    float4 w0_ = *(const float4*)(wp); \
    float4 w1_ = *(const float4*)(wp + 4); \
    h0.x += (XC) * w0_.x; h0.y += (XC) * w0_.y; h0.z += (XC) * w0_.z; h0.w += (XC) * w0_.w; \
    h1.x += (XC) * w1_.x; h1.y += (XC) * w1_.y; h1.z += (XC) * w1_.z; h1.w += (XC) * w1_.w; \
    wp += LDW; }

#define ADJ_STEP(AC) { \
    float4 b0_ = *(const float4*)(hp); \
    float4 b1_ = *(const float4*)(hp + 4); \
    a0.x += (AC) * b0_.x; a0.y += (AC) * b0_.y; a0.z += (AC) * b0_.z; a0.w += (AC) * b0_.w; \
    a1.x += (AC) * b1_.x; a1.y += (AC) * b1_.y; a1.z += (AC) * b1_.z; a1.w += (AC) * b1_.w; \
    hp += LDW; }

__global__ __launch_bounds__(512, 2) void gnn_kernel(
    const int* __restrict__ fp, const float* __restrict__ Aadj,
    const float* __restrict__ embed, const float* __restrict__ Wfp,
    const float* __restrict__ bfp, const float* __restrict__ fc_w,
    const float* __restrict__ fc_b, float* __restrict__ vout)
{
  __shared__ __align__(16) float xs[64 * LDW];   // x, row-major [atom][feat]
  __shared__ __align__(16) float hsb[64 * LDW];  // h, row-major
  __shared__ __align__(16) float Ws[64 * LDW];   // W transposed: Ws[k][o]
  __shared__ float red[512];
  __shared__ float mol[64];

  const int b   = blockIdx.x;
  const int tid = threadIdx.x;
  const int row = tid >> 3;       // atom row this thread owns (0..63)
  const int o0  = (tid & 7) * 8;  // 8 output features per thread

  // x0 = embed[fingerprints]
  for (int idx = tid; idx < 4096; idx += 512) {
    int r = idx >> 6, c = idx & 63;
    xs[r * LDW + c] = embed[(size_t)fp[b * 64 + r] * 64 + c];
  }
  // adjacency diagonal-block row -> registers (block-diagonal exploit)
  float4 Areg[16];
  {
    const float4* arow =
        (const float4*)(Aadj + (size_t)(b * 64 + row) * 8192 + (size_t)b * 64);
#pragma unroll
    for (int q = 0; q < 16; ++q) Areg[q] = arow[q];
  }

  for (int l = 0; l < 3; ++l) {
    // load W transposed: Ws[k][o] = Wfp[l][o][k]
    for (int idx = tid; idx < 4096; idx += 512) {
      int o = idx & 63, k = idx >> 6;
      Ws[k * LDW + o] = Wfp[l * 4096 + o * 64 + k];
    }
    __syncthreads();   // guards Ws writes AND previous-layer xs writes

    // own x row -> registers
    float4 xr[16];
#pragma unroll
    for (int q = 0; q < 16; ++q)
      xr[q] = *(const float4*)&xs[row * LDW + 4 * q];

    // h = relu(x @ W^T + b)
    float4 h0 = *(const float4*)&bfp[l * 64 + o0];
    float4 h1 = *(const float4*)&bfp[l * 64 + o0 + 4];
    {
      const float* wp = &Ws[o0];
#pragma unroll
      for (int k4 = 0; k4 < 16; ++k4) {
        float4 xv = xr[k4];
        GNN_STEP(xv.x) GNN_STEP(xv.y) GNN_STEP(xv.z) GNN_STEP(xv.w)
      }
    }
    h0.x = fmaxf(h0.x, 0.f); h0.y = fmaxf(h0.y, 0.f);
    h0.z = fmaxf(h0.z, 0.f); h0.w = fmaxf(h0.w, 0.f);
    h1.x = fmaxf(h1.x, 0.f); h1.y = fmaxf(h1.y, 0.f);
    h1.z = fmaxf(h1.z, 0.f); h1.w = fmaxf(h1.w, 0.f);
    *(float4*)&hsb[row * LDW + o0]     = h0;
    *(float4*)&hsb[row * LDW + o0 + 4] = h1;
    __syncthreads();

    // hs = h + A @ h  (A row in regs, 0/1 values)
    float4 a0 = h0, a1 = h1;
    {
      const float* hp = &hsb[o0];
#pragma unroll
      for (int j4 = 0; j4 < 16; ++j4) {
        float4 av = Areg[j4];
        ADJ_STEP(av.x) ADJ_STEP(av.y) ADJ_STEP(av.z) ADJ_STEP(av.w)
      }
    }
    // row L2-norm: 8 threads of this row hold 8 feats each -> shuffle reduce
    float ss = a0.x*a0.x + a0.y*a0.y + a0.z*a0.z + a0.w*a0.w
             + a1.x*a1.x + a1.y*a1.y + a1.z*a1.z + a1.w*a1.w;
    ss += __shfl_xor(ss, 1); ss += __shfl_xor(ss, 2); ss += __shfl_xor(ss, 4);
    float inv = 1.0f / fmaxf(sqrtf(ss), 1e-12f);
    a0.x *= inv; a0.y *= inv; a0.z *= inv; a0.w *= inv;
    a1.x *= inv; a1.y *= inv; a1.z *= inv; a1.w *= inv;
    *(float4*)&xs[row * LDW + o0]     = a0;
    *(float4*)&xs[row * LDW + o0 + 4] = a1;
    // next iteration's first __syncthreads guards these writes
  }
  __syncthreads();

  // pool: mol[c] = sum_atoms x[.,c]
  {
    int c = tid & 63, part = tid >> 6;  // 8 parts x 8 rows
    float ps = 0.f;
#pragma unroll
    for (int r = 0; r < 8; ++r) ps += xs[(part * 8 + r) * LDW + c];
    red[part * 64 + c] = ps;
  }
  __syncthreads();
  if (tid < 64) {
    float m = 0.f;
#pragma unroll
    for (int p = 0; p < 8; ++p) m += red[p * 64 + tid];
    mol[tid] = m;
  }
  __syncthreads();
  if (tid < 64) {
    float a = fc_b[tid];
    const float* wr = fc_w + tid * 64;
#pragma unroll 8
    for (int k = 0; k < 64; ++k) a += mol[k] * wr[k];
    vout[b * 64 + tid] = a;
  }
}

// ======================================================================
// QKV projection: grid=128 (token), block=192 (one output each)
// ======================================================================
__global__ __launch_bounds__(192) void qkv_kernel(
    const float* __restrict__ vin, const float* __restrict__ w,
    const float* __restrict__ bias, float* __restrict__ qout)
{
  __shared__ __align__(16) float vr[64];
  const int i = blockIdx.x, tid = threadIdx.x;
  if (tid < 64) vr[tid] = vin[i * 64 + tid];
  __syncthreads();
  const float4* wr = (const float4*)(w + tid * 64);
  float a = bias[tid];
#pragma unroll
  for (int k4 = 0; k4 < 16; ++k4) {
    float4 w4 = wr[k4];
    float4 x4 = *(const float4*)&vr[k4 * 4];
    a += w4.x * x4.x + w4.y * x4.y + w4.z * x4.z + w4.w * x4.w;
  }
  qout[i * 192 + tid] = a;
}

// ======================================================================
// Attention + out-proj + residual + LN1: grid=128 (query token), block=128
// ======================================================================
__global__ __launch_bounds__(128) void attn_kernel(
    const float* __restrict__ vin, const float* __restrict__ qkvb,
    const float* __restrict__ ow, const float* __restrict__ ob,
    const float* __restrict__ gam, const float* __restrict__ bet,
    float* __restrict__ vout)
{
  __shared__ __align__(16) float qrow[64];
  __shared__ float vrow[64];
  __shared__ float P[4][132];     // padded to dodge bank conflicts
  __shared__ float osh[64];
  __shared__ float wred[8], wred2[8];
  const int i = blockIdx.x, tid = threadIdx.x;
  if (tid < 64) { qrow[tid] = qkvb[i * 192 + tid]; vrow[tid] = vin[i * 64 + tid]; }
  __syncthreads();

  const int j = tid;  // key token 0..127
  float s[4];
#pragma unroll
  for (int h = 0; h < 4; ++h) {
    const float4* qp = (const float4*)&qrow[h * 16];
    const float4* kp = (const float4*)(qkvb + j * 192 + 64 + h * 16);
    float a = 0.f;
#pragma unroll
    for (int t = 0; t < 4; ++t) {
      float4 q4 = qp[t], k4 = kp[t];
      a += q4.x * k4.x + q4.y * k4.y + q4.z * k4.z + q4.w * k4.w;
    }
    s[h] = a * 0.25f;  // 1/sqrt(16)
  }
  // per-head max over 128 keys (wave shuffle + cross-wave LDS)
#pragma unroll
  for (int h = 0; h < 4; ++h) {
    float mm = s[h];
    for (int off = 32; off; off >>= 1) mm = fmaxf(mm, __shfl_xor(mm, off));
    if ((tid & 63) == 0) wred[(tid >> 6) * 4 + h] = mm;
  }
  __syncthreads();
  float e[4];
#pragma unroll
  for (int h = 0; h < 4; ++h) e[h] = expf(s[h] - fmaxf(wred[h], wred[4 + h]));
#pragma unroll
  for (int h = 0; h < 4; ++h) {
    float sm = e[h];
    for (int off = 32; off; off >>= 1) sm += __shfl_xor(sm, off);
    if ((tid & 63) == 0) wred2[(tid >> 6) * 4 + h] = sm;
  }
  __syncthreads();
#pragma unroll
  for (int h = 0; h < 4; ++h) P[h][j] = e[h] / (wred2[h] + wred2[4 + h]);
  __syncthreads();

  if (tid < 64) {           // o = attn @ V
    const int d = tid, h = d >> 4;
    float a = 0.f;
    for (int j2 = 0; j2 < 128; ++j2) a += P[h][j2] * qkvb[j2 * 192 + 128 + d];
    osh[d] = a;
  }
  __syncthreads();
  if (tid < 64) {           // out-proj + residual + LN1
    const int d = tid;
    float a = ob[d];
    const float* wr = ow + d * 64;
#pragma unroll 8
    for (int c = 0; c < 64; ++c) a += osh[c] * wr[c];
    float r = vrow[d] + a;
    float mu = r;
    for (int off = 32; off; off >>= 1) mu += __shfl_xor(mu, off);
    mu *= (1.0f / 64.0f);
    float df = r - mu;
    float var = df * df;
    for (int off = 32; off; off >>= 1) var += __shfl_xor(var, off);
    var *= (1.0f / 64.0f);
    vout[i * 64 + d] = df / sqrtf(var + 1e-5f) * gam[d] + bet[d];
  }
}

// ======================================================================
// FFN (64->2048->64) + residual + LN2: grid=128 (token), block=256
// ======================================================================
__global__ __launch_bounds__(256) void ff_kernel(
    const float* __restrict__ vin, const float* __restrict__ w1,
    const float* __restrict__ b1, const float* __restrict__ w2,
    const float* __restrict__ b2, const float* __restrict__ gam,
    const float* __restrict__ bet, float* __restrict__ vout)
{
  __shared__ __align__(16) float vr[64];
  __shared__ __align__(16) float cb[2048];
  __shared__ float rp[4][64];
  const int i = blockIdx.x, tid = threadIdx.x;
  if (tid < 64) vr[tid] = vin[i * 64 + tid];
  __syncthreads();
  // phase 1: hidden activations
#pragma unroll 2
  for (int s = 0; s < 8; ++s) {
    const int jj = tid + 256 * s;
    const float4* wr = (const float4*)(w1 + jj * 64);
    float a = b1[jj];
#pragma unroll
    for (int k4 = 0; k4 < 16; ++k4) {
      float4 w4 = wr[k4];
      float4 x4 = *(const float4*)&vr[k4 * 4];
      a += w4.x * x4.x + w4.y * x4.y + w4.z * x4.z + w4.w * x4.w;
    }
    cb[jj] = fmaxf(a, 0.f);
  }
  __syncthreads();
  // phase 2: project back, 4-way split over hidden dim
  {
    const int d = tid & 63, part = tid >> 6;
    const float4* wr = (const float4*)(w2 + d * 2048 + part * 512);
    float a = 0.f;
#pragma unroll 8
    for (int q = 0; q < 128; ++q) {
      float4 w4 = wr[q];
      float4 c4 = *(const float4*)&cb[part * 512 + q * 4];
      a += w4.x * c4.x + w4.y * c4.y + w4.z * c4.z + w4.w * c4.w;
    }
    rp[part][d] = a;
  }
  __syncthreads();
  if (tid < 64) {
    const int d = tid;
    float r = vr[d] + rp[0][d] + rp[1][d] + rp[2][d] + rp[3][d] + b2[d];
    float mu = r;
    for (int off = 32; off; off >>= 1) mu += __shfl_xor(mu, off);
    mu *= (1.0f / 64.0f);
    float df = r - mu;
    float var = df * df;
    for (int off = 32; off; off >>= 1) var += __shfl_xor(var, off);
    var *= (1.0f / 64.0f);
    vout[i * 64 + d] = df / sqrtf(var + 1e-5f) * gam[d] + bet[d];
  }
}

// ======================================================================
// Output MLP: 2x (64->64 relu) + final 64->2.  grid=128, block=64
// ======================================================================
__global__ __launch_bounds__(64) void head_kernel(
    const float* __restrict__ vin, const float* __restrict__ Ww,
    const float* __restrict__ Wb, const float* __restrict__ Pw,
    const float* __restrict__ Pb, float* __restrict__ out)
{
  __shared__ float h0[64], h1[64];
  const int i = blockIdx.x, d = threadIdx.x;
  h0[d] = vin[i * 64 + d];
  __syncthreads();
  {
    float a = Wb[d];
    const float* wr = Ww + d * 64;
#pragma unroll 8
    for (int c = 0; c < 64; ++c) a += h0[c] * wr[c];
    h1[d] = fmaxf(a, 0.f);
  }
  __syncthreads();
  {
    float a = Wb[64 + d];
    const float* wr = Ww + 4096 + d * 64;
#pragma unroll 8
    for (int c = 0; c < 64; ++c) a += h1[c] * wr[c];
    h0[d] = fmaxf(a, 0.f);   // safe: h0 reads above are done (sync)
  }
  __syncthreads();
  if (d < 2) {
    float a = Pb[d];
    const float* wr = Pw + d * 64;
#pragma unroll 8
    for (int c = 0; c < 64; ++c) a += h0[c] * wr[c];
    out[i * 2 + d] = a;
  }
}

// ======================================================================
extern "C" void kernel_launch(void* const* d_in, const int* in_sizes, int n_in,
                              void* d_out, int out_size, void* d_ws, size_t ws_size,
                              hipStream_t stream) {
  const int*   fp      = (const int*)  d_in[0];
  const float* Aadj    = (const float*)d_in[1];
  const float* embed   = (const float*)d_in[2];
  const float* Wfp     = (const float*)d_in[3];
  const float* bfp     = (const float*)d_in[4];
  const float* fc_w    = (const float*)d_in[5];
  const float* fc_b    = (const float*)d_in[6];
  const float* qkv_w   = (const float*)d_in[7];
  const float* qkv_b   = (const float*)d_in[8];
  const float* out_w   = (const float*)d_in[9];
  const float* out_b   = (const float*)d_in[10];
  const float* ln1_s   = (const float*)d_in[11];
  const float* ln1_b   = (const float*)d_in[12];
  const float* ff1_w   = (const float*)d_in[13];
  const float* ff1_b   = (const float*)d_in[14];
  const float* ff2_w   = (const float*)d_in[15];
  const float* ff2_b   = (const float*)d_in[16];
  const float* ln2_s   = (const float*)d_in[17];
  const float* ln2_b   = (const float*)d_in[18];
  const float* Wout_w  = (const float*)d_in[19];
  const float* Wout_b  = (const float*)d_in[20];
  const float* Wprop_w = (const float*)d_in[21];
  const float* Wprop_b = (const float*)d_in[22];
  float* out = (float*)d_out;

  float* ws  = (float*)d_ws;
  float* vA  = ws;           // [128][64]
  float* vB  = ws + 8192;    // [128][64]
  float* qq  = ws + 16384;   // [128][192]

  gnn_kernel<<<dim3(128), dim3(512), 0, stream>>>(fp, Aadj, embed, Wfp, bfp,
                                                  fc_w, fc_b, vA);
  for (int l = 0; l < 2; ++l) {
    qkv_kernel<<<dim3(128), dim3(192), 0, stream>>>(
        vA, qkv_w + l * 12288, qkv_b + l * 192, qq);
    attn_kernel<<<dim3(128), dim3(128), 0, stream>>>(
        vA, qq, out_w + l * 4096, out_b + l * 64,
        ln1_s + l * 64, ln1_b + l * 64, vB);
    ff_kernel<<<dim3(128), dim3(256), 0, stream>>>(
        vB, ff1_w + l * 131072, ff1_b + l * 2048,
        ff2_w + l * 131072, ff2_b + l * 64,
        ln2_s + l * 64, ln2_b + l * 64, vA);
  }
  head_kernel<<<dim3(128), dim3(64), 0, stream>>>(vA, Wout_w, Wout_b,
                                                  Wprop_w, Wprop_b, out);
}